// Round 4
// baseline (1744.141 us; speedup 1.0000x reference)
//
#include <hip/hip_runtime.h>
#include <hip/hip_fp16.h>

#define TT 1024
#define BB 128
#define II 256
#define HH 256
#define NG 768   // 3*H

// Static scratch (ws_size unknown): x in bf16, wih transposed bf16, gi fp32.
__device__ __align__(16) unsigned short g_xbf[(size_t)TT * BB * II];   // 67 MB
__device__ __align__(16) unsigned short g_wihB[NG * II];               // 384 KB, [n][k]
__device__ __align__(16) float          g_gi[(size_t)TT * BB * NG];    // 402 MB

typedef __attribute__((ext_vector_type(8))) short   bfrag;   // 8 bf16 = 4 VGPR
typedef __attribute__((ext_vector_type(4))) float   f32x4;
typedef __attribute__((ext_vector_type(2))) _Float16 h2t;

__device__ __forceinline__ unsigned short f2bf(float f) {
    unsigned u = __float_as_uint(f);
    return (unsigned short)((u + 0x7fffu + ((u >> 16) & 1u)) >> 16);   // RNE
}
__device__ __forceinline__ unsigned short f2h_bits(float f) {
    return (unsigned short)(__builtin_bit_cast(unsigned,
               __builtin_amdgcn_cvt_pkrtz(f, 0.f)) & 0xffffu);
}
__device__ __forceinline__ unsigned pk2(float a, float b) {
    return __builtin_bit_cast(unsigned, __builtin_amdgcn_cvt_pkrtz(a, b));
}

// ---------------- phase 1a: x f32 -> bf16 ----------------
__global__ void cvt_x_kernel(const float* __restrict__ x) {
    const int n4 = TT * BB * II / 4;
    for (int i = blockIdx.x * blockDim.x + threadIdx.x; i < n4;
         i += gridDim.x * blockDim.x) {
        float4 v = reinterpret_cast<const float4*>(x)[i];
        ushort4 o;
        o.x = f2bf(v.x); o.y = f2bf(v.y); o.z = f2bf(v.z); o.w = f2bf(v.w);
        reinterpret_cast<ushort4*>(g_xbf)[i] = o;
    }
}

// ---------------- phase 1b: wihT [k][n] f32 -> wihB [n][k] bf16 ----------------
__global__ void cvt_wih_kernel(const float* __restrict__ wihT) {
    const int n = blockIdx.x;    // 0..767
    const int k = threadIdx.x;   // 0..255
    g_wihB[n * II + k] = f2bf(wihT[k * NG + n]);
}

// ---------------- phase 2: gi = x @ wihT  (MFMA bf16, fp32 out) ----------------
__global__ void __launch_bounds__(256) gi_gemm_kernel() {
    __shared__ unsigned short Ab[128 * 32];
    __shared__ unsigned short Bb[128 * 32];
    const int tid = threadIdx.x;
    const int mt = blockIdx.x / 6, nt = blockIdx.x % 6;
    const int m0 = mt * 128, n0 = nt * 128;
    const int l = tid & 63, w = tid >> 6;
    const int wr = w >> 1, wc = w & 1;
    const int srow = tid >> 2, scol = (tid & 3) * 8;

    f32x4 acc[4][4] = {};

    for (int ks = 0; ks < 8; ++ks) {
        const int k0 = ks * 32;
        __syncthreads();
        #pragma unroll
        for (int c = 0; c < 2; ++c) {
            const int row = c * 64 + srow;
            *reinterpret_cast<uint4*>(&Ab[row * 32 + scol]) =
                *reinterpret_cast<const uint4*>(&g_xbf[(size_t)(m0 + row) * II + k0 + scol]);
            *reinterpret_cast<uint4*>(&Bb[row * 32 + scol]) =
                *reinterpret_cast<const uint4*>(&g_wihB[(n0 + row) * II + k0 + scol]);
        }
        __syncthreads();
        bfrag af[4], bf[4];
        #pragma unroll
        for (int i = 0; i < 4; ++i) {
            af[i] = *reinterpret_cast<const bfrag*>(
                        &Ab[(wr * 64 + i * 16 + (l & 15)) * 32 + (l >> 4) * 8]);
            bf[i] = *reinterpret_cast<const bfrag*>(
                        &Bb[(wc * 64 + i * 16 + (l & 15)) * 32 + (l >> 4) * 8]);
        }
        #pragma unroll
        for (int mi = 0; mi < 4; ++mi)
            #pragma unroll
            for (int ni = 0; ni < 4; ++ni)
                acc[mi][ni] = __builtin_amdgcn_mfma_f32_16x16x32_bf16(
                                  af[mi], bf[ni], acc[mi][ni], 0, 0, 0);
    }
    #pragma unroll
    for (int mi = 0; mi < 4; ++mi) {
        const int grow = m0 + wr * 64 + mi * 16 + (l >> 4) * 4;
        #pragma unroll
        for (int ni = 0; ni < 4; ++ni) {
            const int gcol = n0 + wc * 64 + ni * 16 + (l & 15);
            #pragma unroll
            for (int q = 0; q < 4; ++q)
                g_gi[(size_t)(grow + q) * NG + gcol] = acc[mi][ni][q];
        }
    }
}

// ---------------- phase 3: recurrence ----------------
// 128 WGs (one per batch row) x 512 threads. Waves 0-3: k in [0,128);
// waves 4-7: k in [128,256). Thread (half, j) holds 64 pairs x 3 gates of
// whh as packed f16x2 in VGPRs (192 words). h ping-pongs in LDS as f16;
// per-wave readlane broadcast (k-half is wave-uniform). gi[t+1] prefetched
// into registers during step t's dot phase.
//
// amdgpu_waves_per_eu(2,2): pin the RA's occupancy target to exactly
// 2 waves/SIMD -> 256-VGPR budget. r2/r3 showed launch_bounds' 2nd arg
// alone leaves the RA targeting 4 waves/SIMD (128 VGPRs) and spilling the
// weight arrays to scratch (64 MB WRITE_SIZE of spill traffic in r3).
__global__ void __launch_bounds__(512)
__attribute__((amdgpu_waves_per_eu(2, 2)))
gru_rec_kernel(
    const float* __restrict__ h0, const float* __restrict__ whhT,
    const float* __restrict__ bias, float* __restrict__ out)
{
    __shared__ unsigned short hpk[2][HH];   // ping-pong h (f16)
    __shared__ float part[NG];              // half1 partial dots

    const int tid  = threadIdx.x;
    const int half = tid >> 8;              // wave-uniform k-half
    const int j    = tid & 255;             // output column
    const int lane = tid & 63;
    const int b    = blockIdx.x;

    // --- weights into VGPRs (fully unrolled: constant indices only) ---
    unsigned wr_[64], wz_[64], wn_[64];
    #pragma unroll
    for (int p = 0; p < 64; ++p) {
        const int k0 = half * 128 + 2 * p;
        const float r0 = whhT[(size_t)k0 * NG + j];
        const float r1 = whhT[(size_t)(k0 + 1) * NG + j];
        const float z0 = whhT[(size_t)k0 * NG + 256 + j];
        const float z1 = whhT[(size_t)(k0 + 1) * NG + 256 + j];
        const float n0 = whhT[(size_t)k0 * NG + 512 + j];
        const float n1 = whhT[(size_t)(k0 + 1) * NG + 512 + j];
        wr_[p] = pk2(r0, r1);
        wz_[p] = pk2(z0, z1);
        wn_[p] = pk2(n0, n1);
    }

    const float br = bias[j], bz = bias[256 + j], bn = bias[512 + j];

    float hprev = 0.f;
    if (half == 0) {
        hprev = h0[b * HH + j];
        hpk[0][j] = f2h_bits(hprev);
    }
    __syncthreads();

    const float* gib = g_gi + (size_t)b * NG + j;
    float giR = 0.f, giZ = 0.f, giN = 0.f;
    if (half == 0) { giR = gib[0]; giZ = gib[256]; giN = gib[512]; }

    for (int t = 0; t < TT; ++t) {
        // prefetch gi[t+1] (registers); consumed next iteration
        float nR = 0.f, nZ = 0.f, nN = 0.f;
        if (half == 0 && t + 1 < TT) {
            const float* gt1 = gib + (size_t)(t + 1) * (BB * NG);
            nR = gt1[0]; nZ = gt1[256]; nN = gt1[512];
        }

        const unsigned* hp32 =
            reinterpret_cast<const unsigned*>(&hpk[t & 1][0]);
        const unsigned src = hp32[half * 64 + lane];   // wave holds 64 pairs

        // 6 accumulator chains for ILP
        float aR = 0.f, aZ = 0.f, aN = 0.f, cR = 0.f, cZ = 0.f, cN = 0.f;
        #pragma unroll
        for (int p = 0; p < 64; ++p) {
            const unsigned hu =
                (unsigned)__builtin_amdgcn_readlane((int)src, p);
            const h2t hh = __builtin_bit_cast(h2t, hu);
            if ((p & 1) == 0) {
                aR = __builtin_amdgcn_fdot2(hh, __builtin_bit_cast(h2t, wr_[p]), aR, false);
                aZ = __builtin_amdgcn_fdot2(hh, __builtin_bit_cast(h2t, wz_[p]), aZ, false);
                aN = __builtin_amdgcn_fdot2(hh, __builtin_bit_cast(h2t, wn_[p]), aN, false);
            } else {
                cR = __builtin_amdgcn_fdot2(hh, __builtin_bit_cast(h2t, wr_[p]), cR, false);
                cZ = __builtin_amdgcn_fdot2(hh, __builtin_bit_cast(h2t, wz_[p]), cZ, false);
                cN = __builtin_amdgcn_fdot2(hh, __builtin_bit_cast(h2t, wn_[p]), cN, false);
            }
        }
        const float accR = aR + cR, accZ = aZ + cZ, accN = aN + cN;

        if (half == 1) {
            part[j]       = accR;
            part[256 + j] = accZ;
            part[512 + j] = accN;
        }
        __syncthreads();
        if (half == 0) {
            const float sR = accR + part[j];
            const float sZ = accZ + part[256 + j];
            const float sN = accN + part[512 + j];
            const float r = 1.f / (1.f + __expf(-(giR + br + sR)));
            const float z = 1.f / (1.f + __expf(-(giZ + bz + sZ)));
            const float e = __expf(2.f * (giN + bn + r * sN));   // tanh
            const float n = 1.f - 2.f / (e + 1.f);
            const float hn = (1.f - z) * n + z * hprev;
            hprev = hn;
            hpk[(t & 1) ^ 1][j] = f2h_bits(hn);
            if (t == TT - 1) out[b * HH + j] = hn;
            giR = nR; giZ = nZ; giN = nN;
        }
        __syncthreads();
    }
}

extern "C" void kernel_launch(void* const* d_in, const int* in_sizes, int n_in,
                              void* d_out, int out_size, void* d_ws, size_t ws_size,
                              hipStream_t stream) {
    const float* x    = (const float*)d_in[0];
    const float* h0   = (const float*)d_in[1];
    const float* wihT = (const float*)d_in[2];
    const float* whhT = (const float*)d_in[3];
    const float* bias = (const float*)d_in[4];
    float*       out  = (float*)d_out;

    cvt_x_kernel<<<2048, 256, 0, stream>>>(x);
    cvt_wih_kernel<<<NG, 256, 0, stream>>>(wihT);
    gi_gemm_kernel<<<1024 * 6, 256, 0, stream>>>();
    gru_rec_kernel<<<BB, 512, 0, stream>>>(h0, whhT, bias, out);
}

// Round 5
// 1699.243 us; speedup vs baseline: 1.0264x; 1.0264x over previous
//
#include <hip/hip_runtime.h>
#include <hip/hip_fp16.h>

#define TT 1024
#define BB 128
#define II 256
#define HH 256
#define NG 768   // 3*H

// Static scratch (ws_size unknown): x in bf16, wih transposed bf16, gi fp32.
__device__ __align__(16) unsigned short g_xbf[(size_t)TT * BB * II];   // 67 MB
__device__ __align__(16) unsigned short g_wihB[NG * II];               // 384 KB, [n][k]
__device__ __align__(16) float          g_gi[(size_t)TT * BB * NG];    // 402 MB

typedef __attribute__((ext_vector_type(8)))  short    bfrag;   // 8 bf16 = 4 VGPR
typedef __attribute__((ext_vector_type(4)))  float    f32x4;
typedef __attribute__((ext_vector_type(2)))  _Float16 h2t;
typedef __attribute__((ext_vector_type(32))) unsigned u32x32;  // weight bank

__device__ __forceinline__ unsigned short f2bf(float f) {
    unsigned u = __float_as_uint(f);
    return (unsigned short)((u + 0x7fffu + ((u >> 16) & 1u)) >> 16);   // RNE
}
__device__ __forceinline__ unsigned short f2h_bits(float f) {
    return (unsigned short)(__builtin_bit_cast(unsigned,
               __builtin_amdgcn_cvt_pkrtz(f, 0.f)) & 0xffffu);
}
__device__ __forceinline__ unsigned pk2(float a, float b) {
    return __builtin_bit_cast(unsigned, __builtin_amdgcn_cvt_pkrtz(a, b));
}

// ---------------- phase 1a: x f32 -> bf16 ----------------
__global__ void cvt_x_kernel(const float* __restrict__ x) {
    const int n4 = TT * BB * II / 4;
    for (int i = blockIdx.x * blockDim.x + threadIdx.x; i < n4;
         i += gridDim.x * blockDim.x) {
        float4 v = reinterpret_cast<const float4*>(x)[i];
        ushort4 o;
        o.x = f2bf(v.x); o.y = f2bf(v.y); o.z = f2bf(v.z); o.w = f2bf(v.w);
        reinterpret_cast<ushort4*>(g_xbf)[i] = o;
    }
}

// ---------------- phase 1b: wihT [k][n] f32 -> wihB [n][k] bf16 ----------------
__global__ void cvt_wih_kernel(const float* __restrict__ wihT) {
    const int n = blockIdx.x;    // 0..767
    const int k = threadIdx.x;   // 0..255
    g_wihB[n * II + k] = f2bf(wihT[k * NG + n]);
}

// ---------------- phase 2: gi = x @ wihT  (MFMA bf16, fp32 out) ----------------
__global__ void __launch_bounds__(256) gi_gemm_kernel() {
    __shared__ unsigned short Ab[128 * 32];
    __shared__ unsigned short Bb[128 * 32];
    const int tid = threadIdx.x;
    const int mt = blockIdx.x / 6, nt = blockIdx.x % 6;
    const int m0 = mt * 128, n0 = nt * 128;
    const int l = tid & 63, w = tid >> 6;
    const int wr = w >> 1, wc = w & 1;
    const int srow = tid >> 2, scol = (tid & 3) * 8;

    f32x4 acc[4][4] = {};

    for (int ks = 0; ks < 8; ++ks) {
        const int k0 = ks * 32;
        __syncthreads();
        #pragma unroll
        for (int c = 0; c < 2; ++c) {
            const int row = c * 64 + srow;
            *reinterpret_cast<uint4*>(&Ab[row * 32 + scol]) =
                *reinterpret_cast<const uint4*>(&g_xbf[(size_t)(m0 + row) * II + k0 + scol]);
            *reinterpret_cast<uint4*>(&Bb[row * 32 + scol]) =
                *reinterpret_cast<const uint4*>(&g_wihB[(n0 + row) * II + k0 + scol]);
        }
        __syncthreads();
        bfrag af[4], bf[4];
        #pragma unroll
        for (int i = 0; i < 4; ++i) {
            af[i] = *reinterpret_cast<const bfrag*>(
                        &Ab[(wr * 64 + i * 16 + (l & 15)) * 32 + (l >> 4) * 8]);
            bf[i] = *reinterpret_cast<const bfrag*>(
                        &Bb[(wc * 64 + i * 16 + (l & 15)) * 32 + (l >> 4) * 8]);
        }
        #pragma unroll
        for (int mi = 0; mi < 4; ++mi)
            #pragma unroll
            for (int ni = 0; ni < 4; ++ni)
                acc[mi][ni] = __builtin_amdgcn_mfma_f32_16x16x32_bf16(
                                  af[mi], bf[ni], acc[mi][ni], 0, 0, 0);
    }
    #pragma unroll
    for (int mi = 0; mi < 4; ++mi) {
        const int grow = m0 + wr * 64 + mi * 16 + (l >> 4) * 4;
        #pragma unroll
        for (int ni = 0; ni < 4; ++ni) {
            const int gcol = n0 + wc * 64 + ni * 16 + (l & 15);
            #pragma unroll
            for (int q = 0; q < 4; ++q)
                g_gi[(size_t)(grow + q) * NG + gcol] = acc[mi][ni][q];
        }
    }
}

// ---------------- phase 3: recurrence ----------------
// 128 WGs (one per batch row) x 1024 threads (16 waves). Thread (q, j):
// q = k-quarter (wave-uniform), j = output column. Each thread holds 32
// pairs x 3 gates of whh = 96 packed f16x2 words in ext_vector registers
// (SSA values -- no SROA/scratch path; ~118 VGPR total fits the 128-VGPR
// budget that a 1024-thread WG forces, so no RA attribute games).
// h ping-pongs in LDS (f16); per-wave readlane broadcast; quarters 1-3
// post partial dots via LDS, quarter 0 does the gate epilogue.
__global__ void __launch_bounds__(1024) gru_rec_kernel(
    const float* __restrict__ h0, const float* __restrict__ whhT,
    const float* __restrict__ bias, float* __restrict__ out)
{
    __shared__ unsigned short hpk[2][HH];   // ping-pong h (f16)
    __shared__ float part[3][NG];           // partials from quarters 1..3

    const int tid  = threadIdx.x;
    const int q    = tid >> 8;              // k-quarter, wave-uniform
    const int j    = tid & 255;             // output column
    const int lane = tid & 63;
    const int b    = blockIdx.x;

    // --- weights into vector registers (forced unroll: constant indices) ---
    u32x32 wr_, wz_, wn_;
    #pragma unroll
    for (int p = 0; p < 32; ++p) {
        const int k0 = q * 64 + 2 * p;
        const float r0 = whhT[(size_t)k0 * NG + j];
        const float r1 = whhT[(size_t)(k0 + 1) * NG + j];
        const float z0 = whhT[(size_t)k0 * NG + 256 + j];
        const float z1 = whhT[(size_t)(k0 + 1) * NG + 256 + j];
        const float n0 = whhT[(size_t)k0 * NG + 512 + j];
        const float n1 = whhT[(size_t)(k0 + 1) * NG + 512 + j];
        wr_[p] = pk2(r0, r1);
        wz_[p] = pk2(z0, z1);
        wn_[p] = pk2(n0, n1);
    }

    float br = 0.f, bz = 0.f, bn = 0.f, hprev = 0.f;
    if (q == 0) {
        br = bias[j]; bz = bias[256 + j]; bn = bias[512 + j];
        hprev = h0[b * HH + j];
        hpk[0][j] = f2h_bits(hprev);
    }
    __syncthreads();

    const float* gib = g_gi + (size_t)b * NG + j;
    float giR = 0.f, giZ = 0.f, giN = 0.f;
    if (q == 0) { giR = gib[0]; giZ = gib[256]; giN = gib[512]; }

    for (int t = 0; t < TT; ++t) {
        // prefetch gi[t+1] (registers); consumed next iteration
        float nR = 0.f, nZ = 0.f, nN = 0.f;
        if (q == 0 && t + 1 < TT) {
            const float* gt1 = gib + (size_t)(t + 1) * (BB * NG);
            nR = gt1[0]; nZ = gt1[256]; nN = gt1[512];
        }

        const unsigned* hp32 =
            reinterpret_cast<const unsigned*>(&hpk[t & 1][0]);
        const unsigned src = hp32[(q << 5) + (lane & 31)];  // quarter's 32 pairs

        // 6 accumulator chains for ILP
        float aR = 0.f, aZ = 0.f, aN = 0.f, cR = 0.f, cZ = 0.f, cN = 0.f;
        #pragma unroll
        for (int p = 0; p < 32; ++p) {
            const unsigned hu =
                (unsigned)__builtin_amdgcn_readlane((int)src, p);
            const h2t hh = __builtin_bit_cast(h2t, hu);
            if ((p & 1) == 0) {
                aR = __builtin_amdgcn_fdot2(hh, __builtin_bit_cast(h2t, (unsigned)wr_[p]), aR, false);
                aZ = __builtin_amdgcn_fdot2(hh, __builtin_bit_cast(h2t, (unsigned)wz_[p]), aZ, false);
                aN = __builtin_amdgcn_fdot2(hh, __builtin_bit_cast(h2t, (unsigned)wn_[p]), aN, false);
            } else {
                cR = __builtin_amdgcn_fdot2(hh, __builtin_bit_cast(h2t, (unsigned)wr_[p]), cR, false);
                cZ = __builtin_amdgcn_fdot2(hh, __builtin_bit_cast(h2t, (unsigned)wz_[p]), cZ, false);
                cN = __builtin_amdgcn_fdot2(hh, __builtin_bit_cast(h2t, (unsigned)wn_[p]), cN, false);
            }
        }
        const float accR = aR + cR, accZ = aZ + cZ, accN = aN + cN;

        if (q != 0) {
            part[q - 1][j]       = accR;
            part[q - 1][256 + j] = accZ;
            part[q - 1][512 + j] = accN;
        }
        __syncthreads();
        if (q == 0) {
            const float sR = accR + part[0][j]       + part[1][j]       + part[2][j];
            const float sZ = accZ + part[0][256 + j] + part[1][256 + j] + part[2][256 + j];
            const float sN = accN + part[0][512 + j] + part[1][512 + j] + part[2][512 + j];
            const float r = 1.f / (1.f + __expf(-(giR + br + sR)));
            const float z = 1.f / (1.f + __expf(-(giZ + bz + sZ)));
            const float e = __expf(2.f * (giN + bn + r * sN));   // tanh
            const float n = 1.f - 2.f / (e + 1.f);
            const float hn = (1.f - z) * n + z * hprev;
            hprev = hn;
            hpk[(t & 1) ^ 1][j] = f2h_bits(hn);
            if (t == TT - 1) out[b * HH + j] = hn;
            giR = nR; giZ = nZ; giN = nN;
        }
        __syncthreads();
    }
}

extern "C" void kernel_launch(void* const* d_in, const int* in_sizes, int n_in,
                              void* d_out, int out_size, void* d_ws, size_t ws_size,
                              hipStream_t stream) {
    const float* x    = (const float*)d_in[0];
    const float* h0   = (const float*)d_in[1];
    const float* wihT = (const float*)d_in[2];
    const float* whhT = (const float*)d_in[3];
    const float* bias = (const float*)d_in[4];
    float*       out  = (float*)d_out;

    cvt_x_kernel<<<2048, 256, 0, stream>>>(x);
    cvt_wih_kernel<<<NG, 256, 0, stream>>>(wihT);
    gi_gemm_kernel<<<1024 * 6, 256, 0, stream>>>();
    gru_rec_kernel<<<BB, 1024, 0, stream>>>(h0, whhT, bias, out);
}

// Round 6
// 1469.313 us; speedup vs baseline: 1.1870x; 1.1565x over previous
//
#include <hip/hip_runtime.h>
#include <hip/hip_fp16.h>

#define TT 1024
#define BB 128
#define II 256
#define HH 256
#define NG 768   // 3*H

// Static scratch (ws_size unknown): x in bf16, wih transposed bf16, gi fp32.
__device__ __align__(16) unsigned short g_xbf[(size_t)TT * BB * II];   // 67 MB
__device__ __align__(16) unsigned short g_wihB[NG * II];               // 384 KB, [n][k]
__device__ __align__(16) float          g_gi[(size_t)TT * BB * NG];    // 402 MB

typedef __attribute__((ext_vector_type(8)))  short    bfrag;   // 8 bf16 = 4 VGPR
typedef __attribute__((ext_vector_type(4)))  float    f32x4;
typedef __attribute__((ext_vector_type(2)))  _Float16 h2t;

__device__ __forceinline__ unsigned short f2bf(float f) {
    unsigned u = __float_as_uint(f);
    return (unsigned short)((u + 0x7fffu + ((u >> 16) & 1u)) >> 16);   // RNE
}
__device__ __forceinline__ unsigned short f2h_bits(float f) {
    return (unsigned short)(__builtin_bit_cast(unsigned,
               __builtin_amdgcn_cvt_pkrtz(f, 0.f)) & 0xffffu);
}
__device__ __forceinline__ unsigned pk2(float a, float b) {
    return __builtin_bit_cast(unsigned, __builtin_amdgcn_cvt_pkrtz(a, b));
}

// ---------------- phase 1a: x f32 -> bf16 ----------------
__global__ void cvt_x_kernel(const float* __restrict__ x) {
    const int n4 = TT * BB * II / 4;
    for (int i = blockIdx.x * blockDim.x + threadIdx.x; i < n4;
         i += gridDim.x * blockDim.x) {
        float4 v = reinterpret_cast<const float4*>(x)[i];
        ushort4 o;
        o.x = f2bf(v.x); o.y = f2bf(v.y); o.z = f2bf(v.z); o.w = f2bf(v.w);
        reinterpret_cast<ushort4*>(g_xbf)[i] = o;
    }
}

// ---------------- phase 1b: wihT [k][n] f32 -> wihB [n][k] bf16 ----------------
__global__ void cvt_wih_kernel(const float* __restrict__ wihT) {
    const int n = blockIdx.x;    // 0..767
    const int k = threadIdx.x;   // 0..255
    g_wihB[n * II + k] = f2bf(wihT[k * NG + n]);
}

// ---------------- phase 2: gi = x @ wihT  (MFMA bf16, fp32 out) ----------------
__global__ void __launch_bounds__(256) gi_gemm_kernel() {
    __shared__ unsigned short Ab[128 * 32];
    __shared__ unsigned short Bb[128 * 32];
    const int tid = threadIdx.x;
    const int mt = blockIdx.x / 6, nt = blockIdx.x % 6;
    const int m0 = mt * 128, n0 = nt * 128;
    const int l = tid & 63, w = tid >> 6;
    const int wr = w >> 1, wc = w & 1;
    const int srow = tid >> 2, scol = (tid & 3) * 8;

    f32x4 acc[4][4] = {};

    for (int ks = 0; ks < 8; ++ks) {
        const int k0 = ks * 32;
        __syncthreads();
        #pragma unroll
        for (int c = 0; c < 2; ++c) {
            const int row = c * 64 + srow;
            *reinterpret_cast<uint4*>(&Ab[row * 32 + scol]) =
                *reinterpret_cast<const uint4*>(&g_xbf[(size_t)(m0 + row) * II + k0 + scol]);
            *reinterpret_cast<uint4*>(&Bb[row * 32 + scol]) =
                *reinterpret_cast<const uint4*>(&g_wihB[(n0 + row) * II + k0 + scol]);
        }
        __syncthreads();
        bfrag af[4], bf[4];
        #pragma unroll
        for (int i = 0; i < 4; ++i) {
            af[i] = *reinterpret_cast<const bfrag*>(
                        &Ab[(wr * 64 + i * 16 + (l & 15)) * 32 + (l >> 4) * 8]);
            bf[i] = *reinterpret_cast<const bfrag*>(
                        &Bb[(wc * 64 + i * 16 + (l & 15)) * 32 + (l >> 4) * 8]);
        }
        #pragma unroll
        for (int mi = 0; mi < 4; ++mi)
            #pragma unroll
            for (int ni = 0; ni < 4; ++ni)
                acc[mi][ni] = __builtin_amdgcn_mfma_f32_16x16x32_bf16(
                                  af[mi], bf[ni], acc[mi][ni], 0, 0, 0);
    }
    #pragma unroll
    for (int mi = 0; mi < 4; ++mi) {
        const int grow = m0 + wr * 64 + mi * 16 + (l >> 4) * 4;
        #pragma unroll
        for (int ni = 0; ni < 4; ++ni) {
            const int gcol = n0 + wc * 64 + ni * 16 + (l & 15);
            #pragma unroll
            for (int q = 0; q < 4; ++q)
                g_gi[(size_t)(grow + q) * NG + gcol] = acc[mi][ni][q];
        }
    }
}

// ---------------- phase 3: recurrence ----------------
// 128 WGs (one per batch row) x 512 threads. Waves 0-3: k in [0,128);
// waves 4-7: k in [128,256). Each thread holds 64 k-pairs x 3 gates of
// whh as 192 INDIVIDUALLY NAMED unsigned scalars (pure SSA: no alloca,
// no array, no dynamic index -> AMDGPUPromoteAlloca cannot send them to
// scratch, which is what silently happened in rounds 2-5; the r2-r5
// kernels all degenerated into L2-streaming the weights at ~1.5us/step).
// waves_per_eu(2,2) gives the RA a 256-VGPR budget for ~235 live values.
// h is read via broadcast ds_read_b128 (all lanes same address).
#define FD(HH2, W, ACC) \
    __builtin_amdgcn_fdot2((HH2), __builtin_bit_cast(h2t, (W)), (ACC), false)

#define INITP(P)                                                                        \
    const unsigned wr##P = pk2(whhT[(size_t)(KB + 2*(P)) * NG + j],                     \
                               whhT[(size_t)(KB + 2*(P) + 1) * NG + j]);                \
    const unsigned wz##P = pk2(whhT[(size_t)(KB + 2*(P)) * NG + 256 + j],               \
                               whhT[(size_t)(KB + 2*(P) + 1) * NG + 256 + j]);          \
    const unsigned wn##P = pk2(whhT[(size_t)(KB + 2*(P)) * NG + 512 + j],               \
                               whhT[(size_t)(KB + 2*(P) + 1) * NG + 512 + j]);
#define I4(A,B,C,D) INITP(A) INITP(B) INITP(C) INITP(D)

#define D3(P, HU)                                                                       \
    { const h2t hh = __builtin_bit_cast(h2t, (unsigned)(HU));                           \
      if (((P) & 1) == 0) { aR = FD(hh, wr##P, aR); aZ = FD(hh, wz##P, aZ);             \
                            aN = FD(hh, wn##P, aN); }                                   \
      else                { cR = FD(hh, wr##P, cR); cZ = FD(hh, wz##P, cZ);             \
                            cN = FD(hh, wn##P, cN); } }

__global__ void __launch_bounds__(512)
__attribute__((amdgpu_waves_per_eu(2, 2)))
gru_rec_kernel(
    const float* __restrict__ h0, const float* __restrict__ whhT,
    const float* __restrict__ bias, float* __restrict__ out)
{
    __shared__ __align__(16) unsigned short hpk[2][HH];   // ping-pong h (f16)
    __shared__ float part[NG];                            // half1 partial dots

    const int tid  = threadIdx.x;
    const int half = tid >> 8;              // wave-uniform k-half
    const int j    = tid & 255;             // output column
    const int b    = blockIdx.x;
    const int KB   = half * 128;            // k-base for this thread

    // --- 192 named weight scalars (f16x2-packed) ---
    I4(0,1,2,3)     I4(4,5,6,7)     I4(8,9,10,11)    I4(12,13,14,15)
    I4(16,17,18,19) I4(20,21,22,23) I4(24,25,26,27)  I4(28,29,30,31)
    I4(32,33,34,35) I4(36,37,38,39) I4(40,41,42,43)  I4(44,45,46,47)
    I4(48,49,50,51) I4(52,53,54,55) I4(56,57,58,59)  I4(60,61,62,63)

    float br = 0.f, bz = 0.f, bn = 0.f, hprev = 0.f;
    if (half == 0) {
        br = bias[j]; bz = bias[256 + j]; bn = bias[512 + j];
        hprev = h0[b * HH + j];
        hpk[0][j] = f2h_bits(hprev);
    }
    __syncthreads();

    const float* gib = g_gi + (size_t)b * NG + j;
    float giR = 0.f, giZ = 0.f, giN = 0.f;
    if (half == 0) { giR = gib[0]; giZ = gib[256]; giN = gib[512]; }

    for (int t = 0; t < TT; ++t) {
        // prefetch gi[t+1] (registers); consumed next iteration
        float nR = 0.f, nZ = 0.f, nN = 0.f;
        if (half == 0 && t + 1 < TT) {
            const float* gt1 = gib + (size_t)(t + 1) * (BB * NG);
            nR = gt1[0]; nZ = gt1[256]; nN = gt1[512];
        }

        // h for this k-half: 128 f16 = 16 b128 broadcast reads (same addr
        // across lanes -> LDS broadcast, no conflicts). 4 groups of 4 so
        // only 16 h-regs are live at once.
        const uint4* hv4 =
            reinterpret_cast<const uint4*>(&hpk[t & 1][KB]);

        float aR = 0.f, aZ = 0.f, aN = 0.f, cR = 0.f, cZ = 0.f, cN = 0.f;
        {
            const uint4 q0 = hv4[0], q1 = hv4[1], q2 = hv4[2], q3 = hv4[3];
            D3(0,q0.x)  D3(1,q0.y)  D3(2,q0.z)  D3(3,q0.w)
            D3(4,q1.x)  D3(5,q1.y)  D3(6,q1.z)  D3(7,q1.w)
            D3(8,q2.x)  D3(9,q2.y)  D3(10,q2.z) D3(11,q2.w)
            D3(12,q3.x) D3(13,q3.y) D3(14,q3.z) D3(15,q3.w)
        }
        {
            const uint4 q0 = hv4[4], q1 = hv4[5], q2 = hv4[6], q3 = hv4[7];
            D3(16,q0.x) D3(17,q0.y) D3(18,q0.z) D3(19,q0.w)
            D3(20,q1.x) D3(21,q1.y) D3(22,q1.z) D3(23,q1.w)
            D3(24,q2.x) D3(25,q2.y) D3(26,q2.z) D3(27,q2.w)
            D3(28,q3.x) D3(29,q3.y) D3(30,q3.z) D3(31,q3.w)
        }
        {
            const uint4 q0 = hv4[8], q1 = hv4[9], q2 = hv4[10], q3 = hv4[11];
            D3(32,q0.x) D3(33,q0.y) D3(34,q0.z) D3(35,q0.w)
            D3(36,q1.x) D3(37,q1.y) D3(38,q1.z) D3(39,q1.w)
            D3(40,q2.x) D3(41,q2.y) D3(42,q2.z) D3(43,q2.w)
            D3(44,q3.x) D3(45,q3.y) D3(46,q3.z) D3(47,q3.w)
        }
        {
            const uint4 q0 = hv4[12], q1 = hv4[13], q2 = hv4[14], q3 = hv4[15];
            D3(48,q0.x) D3(49,q0.y) D3(50,q0.z) D3(51,q0.w)
            D3(52,q1.x) D3(53,q1.y) D3(54,q1.z) D3(55,q1.w)
            D3(56,q2.x) D3(57,q2.y) D3(58,q2.z) D3(59,q2.w)
            D3(60,q3.x) D3(61,q3.y) D3(62,q3.z) D3(63,q3.w)
        }
        const float accR = aR + cR, accZ = aZ + cZ, accN = aN + cN;

        if (half == 1) {
            part[j]       = accR;
            part[256 + j] = accZ;
            part[512 + j] = accN;
        }
        __syncthreads();
        if (half == 0) {
            const float sR = accR + part[j];
            const float sZ = accZ + part[256 + j];
            const float sN = accN + part[512 + j];
            const float r = 1.f / (1.f + __expf(-(giR + br + sR)));
            const float z = 1.f / (1.f + __expf(-(giZ + bz + sZ)));
            const float e = __expf(2.f * (giN + bn + r * sN));   // tanh
            const float n = 1.f - 2.f / (e + 1.f);
            const float hn = (1.f - z) * n + z * hprev;
            hprev = hn;
            hpk[(t & 1) ^ 1][j] = f2h_bits(hn);
            if (t == TT - 1) out[b * HH + j] = hn;
            giR = nR; giZ = nZ; giN = nN;
        }
        __syncthreads();
    }
}

extern "C" void kernel_launch(void* const* d_in, const int* in_sizes, int n_in,
                              void* d_out, int out_size, void* d_ws, size_t ws_size,
                              hipStream_t stream) {
    const float* x    = (const float*)d_in[0];
    const float* h0   = (const float*)d_in[1];
    const float* wihT = (const float*)d_in[2];
    const float* whhT = (const float*)d_in[3];
    const float* bias = (const float*)d_in[4];
    float*       out  = (float*)d_out;

    cvt_x_kernel<<<2048, 256, 0, stream>>>(x);
    cvt_wih_kernel<<<NG, 256, 0, stream>>>(wihT);
    gi_gemm_kernel<<<1024 * 6, 256, 0, stream>>>();
    gru_rec_kernel<<<BB, 512, 0, stream>>>(h0, whhT, bias, out);
}